// Round 6
// baseline (132.374 us; speedup 1.0000x reference)
//
#include <hip/hip_runtime.h>
#include <math.h>

#define ALPHA 0.2f

constexpr int B = 32, N = 1024, F_IN = 512, H = 512;
constexpr int GRID = 512, BLK = 256;                 // 2 blocks/CU -> co-resident w/ 2x margin
constexpr int ROWS_PER_BLOCK = (B * N) / GRID;       // 64
constexpr int ROWS_PER_WAVE  = ROWS_PER_BLOCK / 4;   // 16

typedef float f32x4 __attribute__((ext_vector_type(4)));

// ws layout (floats): u[2*F_IN] | f2[B*N] | bar[2] (as ints)
// f1 is NOT materialized: each wave's attn rows == its f-phase rows, so f1
// lives in registers (butterfly-reduced -> all lanes hold it).

// ---------------------------------------------------------------------------
// K1: u1 = w @ a1, u2 = w @ a2; block 0 also resets the grid-barrier words
// (runs before the fused kernel on the same stream -> deterministic reset
// every launch, including graph replays).
// ---------------------------------------------------------------------------
__global__ __launch_bounds__(64) void u_kernel(const float* __restrict__ w,
                                               const float* __restrict__ a,
                                               float* __restrict__ u,
                                               int* __restrict__ bar) {
    if (blockIdx.x == 0 && threadIdx.x == 0) { bar[0] = 0; bar[1] = 0; }
    const int f = blockIdx.x;      // 0..F_IN-1
    const int l = threadIdx.x;     // 0..63
    const float* wrow = w + (size_t)f * H;
    float s1 = 0.f, s2 = 0.f;
#pragma unroll
    for (int it = 0; it < H / 64; ++it) {
        const int h = l + it * 64;
        const float wv = wrow[h];
        s1 += wv * a[h];
        s2 += wv * a[h + H];
    }
#pragma unroll
    for (int off = 32; off > 0; off >>= 1) {
        s1 += __shfl_xor(s1, off, 64);
        s2 += __shfl_xor(s2, off, 64);
    }
    if (l == 0) { u[f] = s1; u[f + F_IN] = s2; }
}

// softplus(z) on z in [0,1]: ln2 + z/2 + z^2/8 - z^4/192, max err ~3.5e-4.
__device__ __forceinline__ float softplus01(float z) {
    const float z2 = z * z;
    const float t  = fmaf(z2, -5.2083335e-3f, 0.125f);
    return fmaf(z2, t, fmaf(z, 0.5f, 0.69314718f));
}

// ---------------------------------------------------------------------------
// Fused f + attn with a hand-rolled grid barrier (no hipLaunchCooperativeKernel
// -- that silently no-op'd in r5). 512 blocks x 256 thr, launch_bounds(256,2):
// <=2 blocks/CU on 256 CUs, so all 512 are co-resident by capacity -> the
// spin barrier cannot deadlock. Cross-XCD visibility: agent-scope atomics on
// the counter/flag + explicit release/acquire fences (per-XCD L2s are not
// coherent; release writes back L2, acquire invalidates before f2 reads).
// ---------------------------------------------------------------------------
__global__ __launch_bounds__(BLK, 2) void fused_kernel(
        const float* __restrict__ ctx, const int* __restrict__ adj,
        const float* __restrict__ u,   float* __restrict__ f2,
        int* __restrict__ bar,         float* __restrict__ out) {
    const int wave = threadIdx.x >> 6;
    const int lane = threadIdx.x & 63;
    const int baseRow = blockIdx.x * ROWS_PER_BLOCK + wave * ROWS_PER_WAVE;

    // ---- phase A: f1 (registers) / f2 (memory) for this wave's 16 rows ----
    float f1r[ROWS_PER_WAVE];
    {
        const float4* u1p = (const float4*)u;
        const float4* u2p = (const float4*)(u + F_IN);
        const float4 u1a = u1p[lane * 2], u1b = u1p[lane * 2 + 1];
        const float4 u2a = u2p[lane * 2], u2b = u2p[lane * 2 + 1];
#pragma unroll
        for (int i = 0; i < ROWS_PER_WAVE; ++i) {
            const int row = baseRow + i;
            const float4* c4 = (const float4*)(ctx + (size_t)row * F_IN);
            const float4 ca = c4[lane * 2], cb = c4[lane * 2 + 1];
            float s1 = ca.x * u1a.x + ca.y * u1a.y + ca.z * u1a.z + ca.w * u1a.w
                     + cb.x * u1b.x + cb.y * u1b.y + cb.z * u1b.z + cb.w * u1b.w;
            float s2 = ca.x * u2a.x + ca.y * u2a.y + ca.z * u2a.z + ca.w * u2a.w
                     + cb.x * u2b.x + cb.y * u2b.y + cb.z * u2b.z + cb.w * u2b.w;
#pragma unroll
            for (int off = 32; off > 0; off >>= 1) {
                s1 += __shfl_xor(s1, off, 64);
                s2 += __shfl_xor(s2, off, 64);
            }
            f1r[i] = s1;                       // butterfly -> all lanes hold it
            if (lane == 0) f2[row] = s2;
        }
    }

    // ---- prefetch first attn row's adj; completes during the barrier spin
    // (values are from read-only input -> cannot be stale; registers survive
    // the acquire invalidate) ----
    int4 amn[4];
    {
        const int4* arow0 = (const int4*)(adj + (size_t)baseRow * N);
#pragma unroll
        for (int k = 0; k < 4; ++k) amn[k] = arow0[k * 64 + lane];
    }

    // ---- grid barrier ----
    __syncthreads();   // drains this block's f2 stores (vmcnt 0 before s_barrier)
    if (threadIdx.x == 0) {
        __builtin_amdgcn_fence(__ATOMIC_RELEASE, "agent");   // write back L2
        if (__hip_atomic_fetch_add(&bar[0], 1, __ATOMIC_ACQ_REL,
                                   __HIP_MEMORY_SCOPE_AGENT) == GRID - 1)
            __hip_atomic_store(&bar[1], 1, __ATOMIC_RELEASE,
                               __HIP_MEMORY_SCOPE_AGENT);
        while (__hip_atomic_load(&bar[1], __ATOMIC_ACQUIRE,
                                 __HIP_MEMORY_SCOPE_AGENT) == 0)
            __builtin_amdgcn_s_sleep(8);
    }
    __syncthreads();
    __builtin_amdgcn_fence(__ATOMIC_ACQUIRE, "agent");       // invalidate L1/L2

    // ---- phase B: attn for the same 16 rows ----
    const int b = baseRow >> 10;                 // N == 1024
    const f32x4* f2b = (const f32x4*)(f2 + (size_t)b * N);
#pragma unroll
    for (int i = 0; i < ROWS_PER_WAVE; ++i) {
        const int row = baseRow + i;
        int4 am[4];
#pragma unroll
        for (int k = 0; k < 4; ++k) am[k] = amn[k];
        if (i < ROWS_PER_WAVE - 1) {             // pipeline next row's adj
            const int4* arown = (const int4*)(adj + (size_t)(row + 1) * N);
#pragma unroll
            for (int k = 0; k < 4; ++k) amn[k] = arown[k * 64 + lane];
        }

        const float fi = f1r[i];
        float p[16];
        float s = 0.f;
#pragma unroll
        for (int k = 0; k < 4; ++k) {
            const f32x4 fv = f2b[k * 64 + lane];
            float e0 = fi + fv.x; e0 = e0 > 0.f ? e0 : ALPHA * e0;
            float e1 = fi + fv.y; e1 = e1 > 0.f ? e1 : ALPHA * e1;
            float e2 = fi + fv.z; e2 = e2 > 0.f ? e2 : ALPHA * e2;
            float e3 = fi + fv.w; e3 = e3 > 0.f ? e3 : ALPHA * e3;
            const float q0 = (am[k].x > 0) ? __expf(e0) : 0.f;
            const float q1 = (am[k].y > 0) ? __expf(e1) : 0.f;
            const float q2 = (am[k].z > 0) ? __expf(e2) : 0.f;
            const float q3 = (am[k].w > 0) ? __expf(e3) : 0.f;
            p[k * 4 + 0] = q0; p[k * 4 + 1] = q1;
            p[k * 4 + 2] = q2; p[k * 4 + 3] = q3;
            s += (q0 + q1) + (q2 + q3);
        }

#pragma unroll
        for (int off = 32; off > 0; off >>= 1)
            s += __shfl_xor(s, off, 64);
        const float inv = (s > 0.f) ? (1.0f / s) : 0.f;

        f32x4* orow = (f32x4*)(out + (size_t)row * N);
#pragma unroll
        for (int k = 0; k < 4; ++k) {
            f32x4 o;
            o.x = softplus01(p[k * 4 + 0] * inv);
            o.y = softplus01(p[k * 4 + 1] * inv);
            o.z = softplus01(p[k * 4 + 2] * inv);
            o.w = softplus01(p[k * 4 + 3] * inv);
            __builtin_nontemporal_store(o, orow + k * 64 + lane);
        }
    }
}

extern "C" void kernel_launch(void* const* d_in, const int* in_sizes, int n_in,
                              void* d_out, int out_size, void* d_ws, size_t ws_size,
                              hipStream_t stream) {
    const float* ctx = (const float*)d_in[0];   // (B, N, F_IN) f32
    const int*   adj = (const int*)d_in[1];     // (B, N, N) i32
    const float* w   = (const float*)d_in[2];   // (F_IN, H) f32
    const float* a   = (const float*)d_in[3];   // (2H, 1) f32
    float* out = (float*)d_out;                 // (B, N, N) f32

    float* u   = (float*)d_ws;                  // 2*F_IN floats
    float* f2  = u + 2 * F_IN;                  // B*N floats
    int*   bar = (int*)(f2 + B * N);            // 2 ints: arrive count, release

    u_kernel<<<F_IN, 64, 0, stream>>>(w, a, u, bar);
    fused_kernel<<<GRID, BLK, 0, stream>>>(ctx, adj, u, f2, bar, out);
}